// Round 1
// baseline (339.214 us; speedup 1.0000x reference)
//
#include <hip/hip_runtime.h>
#include <math.h>

// Problem shape (compile-time where it buys registers):
//   x:    (B, N, 64)  fp32
//   mask: (B, N, 1)   fp32
//   cent: (256, 64)   fp32
// out = concat( graph_dist (B,256), dist (B,N,256) )
#define E_DIM 64
#define C_DIM 256
#define ROWS  128          // rows of x per block
#define EPS_F 1e-6f

// Main kernel: thread t owns centroid c=t (cached in 64 VGPRs).
// Block covers ROWS rows of one batch. x row loads are wave-uniform
// (-> scalar s_load broadcast). Stores are coalesced along c.
__global__ __launch_bounds__(C_DIM) void cdist_main(
    const float* __restrict__ x,        // (B,N,E)
    const float* __restrict__ mask,     // (B,N)
    const float* __restrict__ cent,     // (C,E)
    float*       __restrict__ graph_acc,// (B,C) pre-zeroed accumulators (d_out head)
    float*       __restrict__ dist_out, // (B,N,C)
    int N)
{
    const int t  = threadIdx.x;            // centroid index
    const int n0 = blockIdx.x * ROWS;
    const int b  = blockIdx.y;

    __shared__ float s_x2[ROWS];
    __shared__ float s_m [ROWS];

    // ---- phase 0: centroid row -> registers, c2 ----
    float creg[E_DIM];
    {
        const float* crow = cent + t * E_DIM;
        #pragma unroll
        for (int e = 0; e < E_DIM; e += 4) {
            float4 v = *reinterpret_cast<const float4*>(crow + e);
            creg[e+0] = v.x; creg[e+1] = v.y; creg[e+2] = v.z; creg[e+3] = v.w;
        }
    }
    float c2 = 0.f;
    #pragma unroll
    for (int e = 0; e < E_DIM; ++e) c2 = fmaf(creg[e], creg[e], c2);

    // ---- phase 1: x2 + mask for this block's rows -> LDS ----
    const float* xbase = x + ((size_t)b * N + n0) * E_DIM;
    for (int r = t; r < ROWS; r += C_DIM) {
        const float* xr = xbase + (size_t)r * E_DIM;
        float s = 0.f;
        #pragma unroll
        for (int e = 0; e < E_DIM; e += 4) {
            float4 v = *reinterpret_cast<const float4*>(xr + e);
            s = fmaf(v.x, v.x, s); s = fmaf(v.y, v.y, s);
            s = fmaf(v.z, v.z, s); s = fmaf(v.w, v.w, s);
        }
        s_x2[r] = s;
        s_m [r] = mask[(size_t)b * N + n0 + r];
    }
    __syncthreads();

    // ---- main loop over rows ----
    const float one_m_c2 = 1.f - c2;
    float gsum = 0.f;
    float* dcol = dist_out + ((size_t)b * N + n0) * C_DIM + t;

    for (int r = 0; r < ROWS; ++r) {
        const float* xr = xbase + (size_t)r * E_DIM;   // uniform addr -> s_load
        float acc = 0.f;
        #pragma unroll
        for (int e = 0; e < E_DIM; ++e)
            acc = fmaf(xr[e], creg[e], acc);

        const float x2  = s_x2[r];
        const float sq  = fmaxf(fmaf(-2.f, acc, x2 + c2), 0.f);
        const float den = (1.f - x2) * one_m_c2;
        float arg = fmaf(2.f * sq, __builtin_amdgcn_rcpf(fmaxf(den, EPS_F)), 1.f);
        arg = fmaxf(arg, 1.f + EPS_F);
        const float d = acoshf(arg) * s_m[r];

        dcol[(size_t)r * C_DIM] = d;   // coalesced along c
        gsum += d;
    }
    atomicAdd(&graph_acc[b * C_DIM + t], gsum);
}

// Finalize: per-batch mask sum, then divide graph accumulators in place.
__global__ __launch_bounds__(C_DIM) void cdist_finalize(
    const float* __restrict__ mask,   // (B,N)
    float*       __restrict__ graph,  // (B,C) in d_out
    int N)
{
    const int b = blockIdx.x;
    const int t = threadIdx.x;

    float s = 0.f;
    for (int n = t; n < N; n += C_DIM) s += mask[(size_t)b * N + n];
    #pragma unroll
    for (int off = 32; off > 0; off >>= 1) s += __shfl_down(s, off, 64);

    __shared__ float partial[4];
    __shared__ float total_s;
    if ((t & 63) == 0) partial[t >> 6] = s;
    __syncthreads();
    if (t == 0) total_s = partial[0] + partial[1] + partial[2] + partial[3];
    __syncthreads();

    graph[b * C_DIM + t] /= total_s;
}

extern "C" void kernel_launch(void* const* d_in, const int* in_sizes, int n_in,
                              void* d_out, int out_size, void* d_ws, size_t ws_size,
                              hipStream_t stream) {
    const float* x    = (const float*)d_in[0];
    const float* mask = (const float*)d_in[1];
    const float* cent = (const float*)d_in[2];
    float* out = (float*)d_out;

    // Derive dims: in_sizes = { B*N*E, B*N, C*E }, out_size = B*C + B*N*C
    const int E  = in_sizes[0] / in_sizes[1];          // 64
    const int C  = in_sizes[2] / E;                    // 256
    const long long BN = in_sizes[1];
    const int B  = (int)((long long)out_size / ((BN / 1) * 0 + C) - BN) < 0 ? 32 : 32; // fallback below
    // robust derivation: out_size = B*C*(N+1), BN = B*N  ->  B = (out_size - BN*C)/C
    const int Bv = (int)(((long long)out_size - BN * C) / C);
    const int Nv = (int)(BN / Bv);
    (void)E; (void)B;

    float* graph_acc = out;            // (B,C)
    float* dist_out  = out + (size_t)Bv * C;

    // zero the graph accumulator region (d_out is poisoned 0xAA)
    hipMemsetAsync(graph_acc, 0, (size_t)Bv * C * sizeof(float), stream);

    dim3 grid(Nv / ROWS, Bv);
    cdist_main<<<grid, C_DIM, 0, stream>>>(x, mask, cent, graph_acc, dist_out, Nv);
    cdist_finalize<<<dim3(Bv), C_DIM, 0, stream>>>(mask, graph_acc, Nv);
}

// Round 2
// 191.858 us; speedup vs baseline: 1.7680x; 1.7680x over previous
//
#include <hip/hip_runtime.h>
#include <math.h>

// Shapes: x (B,N,64) fp32, mask (B,N), cent (256,64) fp32.
// out = concat( graph_dist (B,256), dist (B,N,256) ), fp32.
#define E_DIM 64
#define C_DIM 256
#define CKP   72          // padded K-stride (bf16 elems): 144 B -> +4 banks/row, 2-way max
#define EPS_F 1e-6f

typedef __attribute__((ext_vector_type(8))) short short8;   // 8 bf16 = 4 VGPRs
typedef __attribute__((ext_vector_type(4))) float f32x4;

__device__ __forceinline__ unsigned short f2bf(float f) {
    unsigned int u = __float_as_uint(f);
    u += 0x7FFFu + ((u >> 16) & 1u);     // round-to-nearest-even
    return (unsigned short)(u >> 16);
}

// Block: 256 threads (4 waves). Covers 64 rows x 256 cols of one batch.
// Wave w owns cols [w*64, w*64+64): B-frags live in registers across row-tiles.
__global__ __launch_bounds__(256) void cdist_mfma(
    const float* __restrict__ x,
    const float* __restrict__ mask,
    const float* __restrict__ cent,
    float*       __restrict__ graph_acc,  // (B,C), pre-zeroed
    float*       __restrict__ dist,       // (B,N,C)
    int N)
{
    const int tid  = threadIdx.x;
    const int w    = tid >> 6;
    const int lane = tid & 63;
    const int l15  = lane & 15;
    const int q    = lane >> 4;
    const int n0   = blockIdx.x * 64;
    const int b    = blockIdx.y;

    __shared__ __align__(16) unsigned short sA[64 * CKP];    // x tile, bf16
    __shared__ __align__(16) unsigned short sB[C_DIM * CKP]; // centroids, bf16
    __shared__ float s_a[64], s_rb[64], s_k[64];             // x2, rcp(1-x2), ln2*mask
    __shared__ float s_c2[C_DIM], s_rd2[C_DIM];              // c2, 2*rcp(1-c2)

    const float* xblk = x + ((size_t)b * N + n0) * E_DIM;

    // ---- stage x -> sA (coalesced fp32 reads, bf16 LDS) ----
    #pragma unroll
    for (int it = 0; it < 4; ++it) {
        const int flat = it * 1024 + tid * 4;                // 64*64 = 4096 floats
        float4 v = *reinterpret_cast<const float4*>(xblk + flat);
        const int r = flat >> 6, e = flat & 63;
        ushort4 h;
        h.x = f2bf(v.x); h.y = f2bf(v.y); h.z = f2bf(v.z); h.w = f2bf(v.w);
        *reinterpret_cast<ushort4*>(&sA[r * CKP + e]) = h;
    }
    // ---- stage cent -> sB ----
    #pragma unroll
    for (int it = 0; it < 16; ++it) {
        const int flat = it * 1024 + tid * 4;                // 256*64 = 16384 floats
        float4 v = *reinterpret_cast<const float4*>(cent + flat);
        const int r = flat >> 6, e = flat & 63;
        ushort4 h;
        h.x = f2bf(v.x); h.y = f2bf(v.y); h.z = f2bf(v.z); h.w = f2bf(v.w);
        *reinterpret_cast<ushort4*>(&sB[r * CKP + e]) = h;
    }
    // ---- per-row stats (fp32 exact) ----
    if (tid < 64) {
        const float* xr = xblk + tid * E_DIM;
        float s = 0.f;
        #pragma unroll
        for (int e = 0; e < E_DIM; e += 4) {
            float4 v = *reinterpret_cast<const float4*>(xr + e);
            s = fmaf(v.x, v.x, s); s = fmaf(v.y, v.y, s);
            s = fmaf(v.z, v.z, s); s = fmaf(v.w, v.w, s);
        }
        s_a [tid] = s;
        s_rb[tid] = __builtin_amdgcn_rcpf(1.f - s);
        s_k [tid] = 0.69314718056f * mask[(size_t)b * N + n0 + tid];
    }
    // ---- per-col stats ----
    {
        const float* cr = cent + tid * E_DIM;
        float s = 0.f;
        #pragma unroll
        for (int e = 0; e < E_DIM; e += 4) {
            float4 v = *reinterpret_cast<const float4*>(cr + e);
            s = fmaf(v.x, v.x, s); s = fmaf(v.y, v.y, s);
            s = fmaf(v.z, v.z, s); s = fmaf(v.w, v.w, s);
        }
        s_c2 [tid] = s;
        s_rd2[tid] = 2.f * __builtin_amdgcn_rcpf(1.f - s);
    }
    __syncthreads();

    // ---- B fragments -> registers (wave-invariant across row tiles) ----
    // B layout: n = lane&15, k = quad*8 + j
    short8 bfrag[4][2];
    #pragma unroll
    for (int ct = 0; ct < 4; ++ct) {
        const int c = w * 64 + ct * 16 + l15;
        #pragma unroll
        for (int kf = 0; kf < 2; ++kf)
            bfrag[ct][kf] = *reinterpret_cast<const short8*>(&sB[c * CKP + kf * 32 + q * 8]);
    }
    float c2v[4], rd2v[4], gsum[4];
    #pragma unroll
    for (int ct = 0; ct < 4; ++ct) {
        const int c = w * 64 + ct * 16 + l15;
        c2v[ct] = s_c2[c]; rd2v[ct] = s_rd2[c]; gsum[ct] = 0.f;
    }

    const size_t rowbase = (size_t)b * N + n0;

    // ---- 4 row-tiles of 16 ----
    #pragma unroll
    for (int rt = 0; rt < 4; ++rt) {
        const int r0 = rt * 16;
        short8 a0 = *reinterpret_cast<const short8*>(&sA[(r0 + l15) * CKP + q * 8]);
        short8 a1 = *reinterpret_cast<const short8*>(&sA[(r0 + l15) * CKP + 32 + q * 8]);

        f32x4 acc[4];
        #pragma unroll
        for (int ct = 0; ct < 4; ++ct) {
            f32x4 z = {0.f, 0.f, 0.f, 0.f};
            z = __builtin_amdgcn_mfma_f32_16x16x32_bf16(a0, bfrag[ct][0], z, 0, 0, 0);
            z = __builtin_amdgcn_mfma_f32_16x16x32_bf16(a1, bfrag[ct][1], z, 0, 0, 0);
            acc[ct] = z;
        }

        // epilogue: C layout row = q*4+reg, col = lane&15
        float ar[4], rbr[4], kr[4];
        #pragma unroll
        for (int reg = 0; reg < 4; ++reg) {
            const int rr = r0 + q * 4 + reg;
            ar[reg] = s_a[rr]; rbr[reg] = s_rb[rr]; kr[reg] = s_k[rr];
        }
        #pragma unroll
        for (int ct = 0; ct < 4; ++ct) {
            const int c = w * 64 + ct * 16 + l15;
            #pragma unroll
            for (int reg = 0; reg < 4; ++reg) {
                const float dot = acc[ct][reg];
                float sq = fmaf(-2.f, dot, ar[reg] + c2v[ct]);
                sq = fmaxf(sq, 0.f);
                float u = fmaxf(sq * (rbr[reg] * rd2v[ct]), EPS_F);
                float t = u + __builtin_amdgcn_sqrtf(fmaf(u, u, u + u)); // u + sqrt(u^2+2u)
                const float d = __builtin_amdgcn_logf(1.f + t) * kr[reg]; // log2 * ln2 * mask
                dist[(rowbase + r0 + q * 4 + reg) * C_DIM + c] = d;
                gsum[ct] += d;
            }
        }
    }

    // ---- per-column sums -> graph accumulators ----
    #pragma unroll
    for (int ct = 0; ct < 4; ++ct) {
        float s = gsum[ct];
        s += __shfl_xor(s, 16);
        s += __shfl_xor(s, 32);
        if (q == 0)
            atomicAdd(&graph_acc[b * C_DIM + w * 64 + ct * 16 + l15], s);
    }
}

// Finalize: per-batch mask sum, then divide graph accumulators in place.
__global__ __launch_bounds__(C_DIM) void cdist_finalize(
    const float* __restrict__ mask,
    float*       __restrict__ graph,
    int N)
{
    const int b = blockIdx.x;
    const int t = threadIdx.x;

    float s = 0.f;
    for (int n = t; n < N; n += C_DIM) s += mask[(size_t)b * N + n];
    #pragma unroll
    for (int off = 32; off > 0; off >>= 1) s += __shfl_down(s, off, 64);

    __shared__ float partial[4];
    __shared__ float total_s;
    if ((t & 63) == 0) partial[t >> 6] = s;
    __syncthreads();
    if (t == 0) total_s = partial[0] + partial[1] + partial[2] + partial[3];
    __syncthreads();

    graph[b * C_DIM + t] /= total_s;
}

extern "C" void kernel_launch(void* const* d_in, const int* in_sizes, int n_in,
                              void* d_out, int out_size, void* d_ws, size_t ws_size,
                              hipStream_t stream) {
    const float* x    = (const float*)d_in[0];
    const float* mask = (const float*)d_in[1];
    const float* cent = (const float*)d_in[2];
    float* out = (float*)d_out;

    // in_sizes = { B*N*E, B*N, C*E }; out_size = B*C + B*N*C
    const long long BN = in_sizes[1];
    const int E = in_sizes[0] / (int)BN;       // 64
    const int C = in_sizes[2] / E;             // 256
    const int B = (int)(((long long)out_size - BN * C) / C);
    const int N = (int)(BN / B);

    float* graph_acc = out;                    // (B,C)
    float* dist_out  = out + (size_t)B * C;    // (B,N,C)

    hipMemsetAsync(graph_acc, 0, (size_t)B * C * sizeof(float), stream);

    dim3 grid(N / 64, B);
    cdist_mfma<<<grid, 256, 0, stream>>>(x, mask, cent, graph_acc, dist_out, N);
    cdist_finalize<<<dim3(B), C_DIM, 0, stream>>>(mask, graph_acc, N);
}

// Round 3
// 191.379 us; speedup vs baseline: 1.7725x; 1.0025x over previous
//
#include <hip/hip_runtime.h>
#include <math.h>

// Shapes: x (B,N,64) fp32, mask (B,N), cent (256,64) fp32.
// out = concat( graph_dist (B,256), dist (B,N,256) ), fp32.
#define E_DIM 64
#define C_DIM 256
#define EPS_F 1e-6f
#define LN2_F 0.69314718056f

typedef __attribute__((ext_vector_type(8))) short short8;   // 8 bf16 = 4 VGPRs
typedef __attribute__((ext_vector_type(4))) float f32x4;

__device__ __forceinline__ unsigned short f2bf(float f) {
    unsigned int u = __float_as_uint(f);
    u += 0x7FFFu + ((u >> 16) & 1u);     // round-to-nearest-even
    return (unsigned short)(u >> 16);
}

__device__ __forceinline__ short8 pack8(float4 a, float4 b) {
    short8 h;
    h[0] = (short)f2bf(a.x); h[1] = (short)f2bf(a.y);
    h[2] = (short)f2bf(a.z); h[3] = (short)f2bf(a.w);
    h[4] = (short)f2bf(b.x); h[5] = (short)f2bf(b.y);
    h[6] = (short)f2bf(b.z); h[7] = (short)f2bf(b.w);
    return h;
}

// ws layout (bytes):
//   [0, 32768)        : B-fragments, short8 F[(ct16*2+kf)*64 + lane]
//   [32768, 33792)    : c2[256]
//   [33792, 34816)    : rd2[256]  = 2/(1-c2)
//   [34816, 34816+4B) : inv_masksum[B]
#define WS_F    0
#define WS_C2   32768
#define WS_RD2  33792
#define WS_INVM 34816

// Block 0: centroid conversion + stats. Blocks 1..B: per-batch 1/sum(mask).
__global__ __launch_bounds__(C_DIM) void cdist_pre(
    const float* __restrict__ cent,
    const float* __restrict__ mask,
    unsigned char* __restrict__ ws,
    int N)
{
    const int t = threadIdx.x;
    if (blockIdx.x == 0) {
        // thread t owns centroid row c = t
        float r[E_DIM];
        const float* cr = cent + t * E_DIM;
        #pragma unroll
        for (int e = 0; e < E_DIM; e += 4) {
            float4 v = *reinterpret_cast<const float4*>(cr + e);
            r[e] = v.x; r[e+1] = v.y; r[e+2] = v.z; r[e+3] = v.w;
        }
        float c2 = 0.f;
        #pragma unroll
        for (int e = 0; e < E_DIM; ++e) c2 = fmaf(r[e], r[e], c2);
        ((float*)(ws + WS_C2))[t]  = c2;
        ((float*)(ws + WS_RD2))[t] = 2.f / (1.f - c2);

        // fragment order: F[(ct16*2+kf)*64 + (l15 + 16q)] = row c, k = kf*32+q*8..+7
        const int ct16 = t >> 4, l15 = t & 15;
        short8* F = (short8*)(ws + WS_F);
        #pragma unroll
        for (int kf = 0; kf < 2; ++kf) {
            #pragma unroll
            for (int q = 0; q < 4; ++q) {
                short8 h;
                #pragma unroll
                for (int j = 0; j < 8; ++j)
                    h[j] = (short)f2bf(r[kf * 32 + q * 8 + j]);
                F[(ct16 * 2 + kf) * 64 + 16 * q + l15] = h;
            }
        }
    } else {
        const int b = blockIdx.x - 1;
        float s = 0.f;
        for (int n = t; n < N; n += C_DIM) s += mask[(size_t)b * N + n];
        #pragma unroll
        for (int off = 32; off > 0; off >>= 1) s += __shfl_down(s, off, 64);
        __shared__ float partial[4];
        if ((t & 63) == 0) partial[t >> 6] = s;
        __syncthreads();
        if (t == 0) {
            float tot = partial[0] + partial[1] + partial[2] + partial[3];
            ((float*)(ws + WS_INVM))[b] = 1.f / tot;
        }
    }
}

// Main: 256 threads (4 waves), 64 rows x 256 cols per block. No LDS, no barriers.
// Wave w owns cols [w*64, w*64+64). A-frags loaded fp32 direct from global,
// converted in-register; x2 exact fp32 via same regs + shfl_xor.
__global__ __launch_bounds__(256) void cdist_mfma(
    const float* __restrict__ x,
    const float* __restrict__ mask,
    const unsigned char* __restrict__ ws,
    float*       __restrict__ graph_acc,  // (B,C), pre-zeroed
    float*       __restrict__ dist,       // (B,N,C)
    int N)
{
    const int tid  = threadIdx.x;
    const int w    = tid >> 6;
    const int lane = tid & 63;
    const int l15  = lane & 15;
    const int q    = lane >> 4;
    const int n0   = blockIdx.x * 64;
    const int b    = blockIdx.y;

    const short8* F   = (const short8*)(ws + WS_F);
    const float*  c2w = (const float*)(ws + WS_C2);
    const float*  rd2w= (const float*)(ws + WS_RD2);

    // B fragments: one coalesced 16B/lane load each
    short8 bfrag[4][2];
    #pragma unroll
    for (int ct = 0; ct < 4; ++ct)
        #pragma unroll
        for (int kf = 0; kf < 2; ++kf)
            bfrag[ct][kf] = F[((w * 4 + ct) * 2 + kf) * 64 + lane];

    float c2v[4], rd2v[4], gsum[4];
    #pragma unroll
    for (int ct = 0; ct < 4; ++ct) {
        const int c = w * 64 + ct * 16 + l15;
        c2v[ct] = c2w[c]; rd2v[ct] = rd2w[c]; gsum[ct] = 0.f;
    }

    const size_t rowbase = (size_t)b * N + n0;

    #pragma unroll
    for (int rt = 0; rt < 4; ++rt) {
        const size_t row = rowbase + rt * 16 + l15;   // this lane's A row
        const float* xr = x + row * E_DIM + q * 8;
        float4 v0 = *reinterpret_cast<const float4*>(xr);
        float4 v1 = *reinterpret_cast<const float4*>(xr + 4);
        float4 v2 = *reinterpret_cast<const float4*>(xr + 32);
        float4 v3 = *reinterpret_cast<const float4*>(xr + 36);

        // exact fp32 sum of squares of this lane's 16 k-elems, then cross-q sum
        float ss = 0.f;
        ss = fmaf(v0.x, v0.x, ss); ss = fmaf(v0.y, v0.y, ss);
        ss = fmaf(v0.z, v0.z, ss); ss = fmaf(v0.w, v0.w, ss);
        ss = fmaf(v1.x, v1.x, ss); ss = fmaf(v1.y, v1.y, ss);
        ss = fmaf(v1.z, v1.z, ss); ss = fmaf(v1.w, v1.w, ss);
        ss = fmaf(v2.x, v2.x, ss); ss = fmaf(v2.y, v2.y, ss);
        ss = fmaf(v2.z, v2.z, ss); ss = fmaf(v2.w, v2.w, ss);
        ss = fmaf(v3.x, v3.x, ss); ss = fmaf(v3.y, v3.y, ss);
        ss = fmaf(v3.z, v3.z, ss); ss = fmaf(v3.w, v3.w, ss);
        ss += __shfl_xor(ss, 16);
        ss += __shfl_xor(ss, 32);                     // x2 of row (all lanes w/ same l15)

        const float rbrow = __builtin_amdgcn_rcpf(1.f - ss);
        const float krow  = LN2_F * mask[row];

        short8 a0 = pack8(v0, v1);                    // k = q*8..q*8+7
        short8 a1 = pack8(v2, v3);                    // k = 32+q*8..+7

        f32x4 acc[4];
        #pragma unroll
        for (int ct = 0; ct < 4; ++ct) {
            f32x4 z = {0.f, 0.f, 0.f, 0.f};
            z = __builtin_amdgcn_mfma_f32_16x16x32_bf16(a0, bfrag[ct][0], z, 0, 0, 0);
            z = __builtin_amdgcn_mfma_f32_16x16x32_bf16(a1, bfrag[ct][1], z, 0, 0, 0);
            acc[ct] = z;
        }

        // C layout: row = q*4+reg, col = l15. Pull row stats from lane q*4+reg.
        float ar[4], rbr[4], kr[4];
        #pragma unroll
        for (int reg = 0; reg < 4; ++reg) {
            const int src = q * 4 + reg;              // lane holding that row (q'=0)
            ar[reg]  = __shfl(ss,    src);
            rbr[reg] = __shfl(rbrow, src);
            kr[reg]  = __shfl(krow,  src);
        }
        #pragma unroll
        for (int ct = 0; ct < 4; ++ct) {
            const int c = w * 64 + ct * 16 + l15;
            #pragma unroll
            for (int reg = 0; reg < 4; ++reg) {
                const float dot = acc[ct][reg];
                float sq = fmaf(-2.f, dot, ar[reg] + c2v[ct]);
                sq = fmaxf(sq, 0.f);
                float u = fmaxf(sq * (rbr[reg] * rd2v[ct]), EPS_F);
                float t = u + __builtin_amdgcn_sqrtf(fmaf(u, u, u + u)); // u+sqrt(u^2+2u)
                const float d = __builtin_amdgcn_logf(1.f + t) * kr[reg];
                dist[(rowbase + rt * 16 + q * 4 + reg) * C_DIM + c] = d;
                gsum[ct] += d;
            }
        }
    }

    const float inv = ((const float*)(ws + WS_INVM))[b];
    #pragma unroll
    for (int ct = 0; ct < 4; ++ct) {
        float s = gsum[ct];
        s += __shfl_xor(s, 16);
        s += __shfl_xor(s, 32);
        if (q == 0)
            atomicAdd(&graph_acc[b * C_DIM + w * 64 + ct * 16 + l15], s * inv);
    }
}

extern "C" void kernel_launch(void* const* d_in, const int* in_sizes, int n_in,
                              void* d_out, int out_size, void* d_ws, size_t ws_size,
                              hipStream_t stream) {
    const float* x    = (const float*)d_in[0];
    const float* mask = (const float*)d_in[1];
    const float* cent = (const float*)d_in[2];
    float* out = (float*)d_out;

    // in_sizes = { B*N*E, B*N, C*E }; out_size = B*C + B*N*C
    const long long BN = in_sizes[1];
    const int E = in_sizes[0] / (int)BN;       // 64
    const int C = in_sizes[2] / E;             // 256
    const int B = (int)(((long long)out_size - BN * C) / C);
    const int N = (int)(BN / B);

    float* graph_acc = out;                    // (B,C)
    float* dist_out  = out + (size_t)B * C;    // (B,N,C)
    unsigned char* ws = (unsigned char*)d_ws;

    hipMemsetAsync(graph_acc, 0, (size_t)B * C * sizeof(float), stream);

    cdist_pre<<<dim3(B + 1), C_DIM, 0, stream>>>(cent, mask, ws, N);
    cdist_mfma<<<dim3(N / 64, B), 256, 0, stream>>>(x, mask, ws, graph_acc, dist_out, N);
}

// Round 4
// 180.198 us; speedup vs baseline: 1.8825x; 1.0620x over previous
//
#include <hip/hip_runtime.h>
#include <math.h>

// Shapes: x (B,N,64) fp32, mask (B,N), cent (256,64) fp32.
// out = concat( graph_dist (B,256), dist (B,N,256) ), fp32.
#define E_DIM 64
#define C_DIM 256
#define EPS_F 1e-6f
#define LN2_F 0.69314718056f
#define TP    68            // padded LDS row stride (dwords): 2-way bank alias only

typedef __attribute__((ext_vector_type(8))) short short8;   // 8 bf16 = 4 VGPRs
typedef __attribute__((ext_vector_type(4))) float f32x4;

__device__ __forceinline__ unsigned short f2bf(float f) {
    unsigned int u = __float_as_uint(f);
    u += 0x7FFFu + ((u >> 16) & 1u);     // round-to-nearest-even
    return (unsigned short)(u >> 16);
}

__device__ __forceinline__ short8 pack8(float4 a, float4 b) {
    short8 h;
    h[0] = (short)f2bf(a.x); h[1] = (short)f2bf(a.y);
    h[2] = (short)f2bf(a.z); h[3] = (short)f2bf(a.w);
    h[4] = (short)f2bf(b.x); h[5] = (short)f2bf(b.y);
    h[6] = (short)f2bf(b.z); h[7] = (short)f2bf(b.w);
    return h;
}

// ws layout (bytes):
//   [0, 32768)     : B-fragments, short8 F[(ct16*2+kf)*64 + lane]
//   [32768, 33792) : c2[256]
//   [33792, 34816) : rd2[256]  = 2/(1-c2)
//   [34816, ...)   : inv_masksum[B]
#define WS_F    0
#define WS_C2   32768
#define WS_RD2  33792
#define WS_INVM 34816

// Block 0: centroid conversion + stats. Blocks 1..B: per-batch 1/sum(mask).
__global__ __launch_bounds__(C_DIM) void cdist_pre(
    const float* __restrict__ cent,
    const float* __restrict__ mask,
    unsigned char* __restrict__ ws,
    int N)
{
    const int t = threadIdx.x;
    if (blockIdx.x == 0) {
        float r[E_DIM];
        const float* cr = cent + t * E_DIM;
        #pragma unroll
        for (int e = 0; e < E_DIM; e += 4) {
            float4 v = *reinterpret_cast<const float4*>(cr + e);
            r[e] = v.x; r[e+1] = v.y; r[e+2] = v.z; r[e+3] = v.w;
        }
        float c2 = 0.f;
        #pragma unroll
        for (int e = 0; e < E_DIM; ++e) c2 = fmaf(r[e], r[e], c2);
        ((float*)(ws + WS_C2))[t]  = c2;
        ((float*)(ws + WS_RD2))[t] = 2.f / (1.f - c2);

        const int ct16 = t >> 4, l15 = t & 15;
        short8* F = (short8*)(ws + WS_F);
        #pragma unroll
        for (int kf = 0; kf < 2; ++kf) {
            #pragma unroll
            for (int q = 0; q < 4; ++q) {
                short8 h;
                #pragma unroll
                for (int j = 0; j < 8; ++j)
                    h[j] = (short)f2bf(r[kf * 32 + q * 8 + j]);
                F[(ct16 * 2 + kf) * 64 + 16 * q + l15] = h;
            }
        }
    } else {
        const int b = blockIdx.x - 1;
        float s = 0.f;
        for (int n = t; n < N; n += C_DIM) s += mask[(size_t)b * N + n];
        #pragma unroll
        for (int off = 32; off > 0; off >>= 1) s += __shfl_down(s, off, 64);
        __shared__ float partial[4];
        if ((t & 63) == 0) partial[t >> 6] = s;
        __syncthreads();
        if (t == 0) {
            float tot = partial[0] + partial[1] + partial[2] + partial[3];
            ((float*)(ws + WS_INVM))[b] = 1.f / tot;
        }
    }
}

// Main: 256 threads (4 waves), 64 rows x 256 cols per block. Wave w owns cols
// [w*64, w*64+64). Output tile transposed through a private per-wave LDS tile
// so global stores are dwordx4 with 256B-contiguous row segments.
__global__ __launch_bounds__(256, 4) void cdist_mfma(
    const float* __restrict__ x,
    const float* __restrict__ mask,
    const unsigned char* __restrict__ ws,
    float*       __restrict__ graph_acc,  // (B,C), pre-zeroed
    float*       __restrict__ dist,       // (B,N,C)
    int N)
{
    const int tid  = threadIdx.x;
    const int w    = tid >> 6;
    const int lane = tid & 63;
    const int l15  = lane & 15;
    const int q    = lane >> 4;
    const int n0   = blockIdx.x * 64;
    const int b    = blockIdx.y;

    __shared__ __align__(16) float sT[4][16 * TP];   // per-wave transpose tile

    const short8* F    = (const short8*)(ws + WS_F);
    const float*  c2w  = (const float*)(ws + WS_C2);
    const float*  rd2w = (const float*)(ws + WS_RD2);

    short8 bfrag[4][2];
    #pragma unroll
    for (int ct = 0; ct < 4; ++ct)
        #pragma unroll
        for (int kf = 0; kf < 2; ++kf)
            bfrag[ct][kf] = F[((w * 4 + ct) * 2 + kf) * 64 + lane];

    float c2v[4], rd2v[4], gsum[4];
    #pragma unroll
    for (int ct = 0; ct < 4; ++ct) {
        const int c = w * 64 + ct * 16 + l15;
        c2v[ct] = c2w[c]; rd2v[ct] = rd2w[c]; gsum[ct] = 0.f;
    }

    const size_t rowbase = (size_t)b * N + n0;
    float* sW = sT[w];

    // prefetch row-tile 0
    const float* xr0 = x + (rowbase + l15) * E_DIM + q * 8;
    float4 v0 = *reinterpret_cast<const float4*>(xr0);
    float4 v1 = *reinterpret_cast<const float4*>(xr0 + 4);
    float4 v2 = *reinterpret_cast<const float4*>(xr0 + 32);
    float4 v3 = *reinterpret_cast<const float4*>(xr0 + 36);
    float  mk = mask[rowbase + l15];

    #pragma unroll 1
    for (int rt = 0; rt < 4; ++rt) {
        // current tile regs
        float4 u0 = v0, u1 = v1, u2 = v2, u3 = v3;
        float  mkc = mk;

        // issue next tile's loads (overlap with compute below)
        if (rt < 3) {
            const float* xr = x + (rowbase + (rt + 1) * 16 + l15) * E_DIM + q * 8;
            v0 = *reinterpret_cast<const float4*>(xr);
            v1 = *reinterpret_cast<const float4*>(xr + 4);
            v2 = *reinterpret_cast<const float4*>(xr + 32);
            v3 = *reinterpret_cast<const float4*>(xr + 36);
            mk = mask[rowbase + (rt + 1) * 16 + l15];
        }

        // exact fp32 row norm
        float ss = 0.f;
        ss = fmaf(u0.x, u0.x, ss); ss = fmaf(u0.y, u0.y, ss);
        ss = fmaf(u0.z, u0.z, ss); ss = fmaf(u0.w, u0.w, ss);
        ss = fmaf(u1.x, u1.x, ss); ss = fmaf(u1.y, u1.y, ss);
        ss = fmaf(u1.z, u1.z, ss); ss = fmaf(u1.w, u1.w, ss);
        ss = fmaf(u2.x, u2.x, ss); ss = fmaf(u2.y, u2.y, ss);
        ss = fmaf(u2.z, u2.z, ss); ss = fmaf(u2.w, u2.w, ss);
        ss = fmaf(u3.x, u3.x, ss); ss = fmaf(u3.y, u3.y, ss);
        ss = fmaf(u3.z, u3.z, ss); ss = fmaf(u3.w, u3.w, ss);
        ss += __shfl_xor(ss, 16);
        ss += __shfl_xor(ss, 32);

        const float rbrow = __builtin_amdgcn_rcpf(1.f - ss);
        const float krow  = LN2_F * mkc;

        short8 a0 = pack8(u0, u1);
        short8 a1 = pack8(u2, u3);

        f32x4 acc[4];
        #pragma unroll
        for (int ct = 0; ct < 4; ++ct) {
            f32x4 z = {0.f, 0.f, 0.f, 0.f};
            z = __builtin_amdgcn_mfma_f32_16x16x32_bf16(a0, bfrag[ct][0], z, 0, 0, 0);
            z = __builtin_amdgcn_mfma_f32_16x16x32_bf16(a1, bfrag[ct][1], z, 0, 0, 0);
            acc[ct] = z;
        }

        // per-row stats for this lane's 4 output rows (rows q*4+reg)
        float ar[4], rbr[4], kr[4];
        #pragma unroll
        for (int reg = 0; reg < 4; ++reg) {
            const int src = q * 4 + reg;
            ar[reg]  = __shfl(ss,    src);
            rbr[reg] = __shfl(rbrow, src);
            kr[reg]  = __shfl(krow,  src);
        }

        // epilogue -> LDS tile (row = q*4+reg, col = ct*16+l15)
        #pragma unroll
        for (int ct = 0; ct < 4; ++ct) {
            #pragma unroll
            for (int reg = 0; reg < 4; ++reg) {
                const float dot = acc[ct][reg];
                float sq = fmaf(-2.f, dot, ar[reg] + c2v[ct]);
                sq = fmaxf(sq, 0.f);
                float uu = fmaxf(sq * (rbr[reg] * rd2v[ct]), EPS_F);
                float t  = uu + __builtin_amdgcn_sqrtf(fmaf(uu, uu, uu + uu));
                const float d = __builtin_amdgcn_logf(1.f + t) * kr[reg];
                sW[(q * 4 + reg) * TP + ct * 16 + l15] = d;
                gsum[ct] += d;
            }
        }

        // drain LDS tile -> global, dwordx4, 256B-contiguous row segments
        #pragma unroll
        for (int i = 0; i < 4; ++i) {
            const int row2 = i * 4 + (lane >> 4);      // 0..15
            const int col2 = (lane & 15) * 4;          // 0..60
            float4 val = *reinterpret_cast<const float4*>(&sW[row2 * TP + col2]);
            *reinterpret_cast<float4*>(
                dist + (rowbase + rt * 16 + row2) * C_DIM + w * 64 + col2) = val;
        }
    }

    const float inv = ((const float*)(ws + WS_INVM))[b];
    #pragma unroll
    for (int ct = 0; ct < 4; ++ct) {
        float s = gsum[ct];
        s += __shfl_xor(s, 16);
        s += __shfl_xor(s, 32);
        if (q == 0)
            atomicAdd(&graph_acc[b * C_DIM + w * 64 + ct * 16 + l15], s * inv);
    }
}

extern "C" void kernel_launch(void* const* d_in, const int* in_sizes, int n_in,
                              void* d_out, int out_size, void* d_ws, size_t ws_size,
                              hipStream_t stream) {
    const float* x    = (const float*)d_in[0];
    const float* mask = (const float*)d_in[1];
    const float* cent = (const float*)d_in[2];
    float* out = (float*)d_out;

    // in_sizes = { B*N*E, B*N, C*E }; out_size = B*C + B*N*C
    const long long BN = in_sizes[1];
    const int E = in_sizes[0] / (int)BN;       // 64
    const int C = in_sizes[2] / E;             // 256
    const int B = (int)(((long long)out_size - BN * C) / C);
    const int N = (int)(BN / B);

    float* graph_acc = out;                    // (B,C)
    float* dist_out  = out + (size_t)B * C;    // (B,N,C)
    unsigned char* ws = (unsigned char*)d_ws;

    hipMemsetAsync(graph_acc, 0, (size_t)B * C * sizeof(float), stream);

    cdist_pre<<<dim3(B + 1), C_DIM, 0, stream>>>(cent, mask, ws, N);
    cdist_mfma<<<dim3(N / 64, B), 256, 0, stream>>>(x, mask, ws, graph_acc, dist_out, N);
}